// Round 2
// baseline (455.886 us; speedup 1.0000x reference)
//
#include <hip/hip_runtime.h>

#define HID 1024
#define ADP 256
#define MB  32

typedef short s16x8 __attribute__((ext_vector_type(8)));
typedef float f32x4 __attribute__((ext_vector_type(4)));

__device__ __forceinline__ unsigned short f2bf(float f) {
    union { float f; unsigned int u; } v; v.f = f;
    unsigned int r = v.u + 0x7fffu + ((v.u >> 16) & 1u);   // round-to-nearest-even
    return (unsigned short)(r >> 16);
}

__device__ __forceinline__ float bf2f(unsigned short u) {
    union { unsigned int u; float f; } v; v.u = ((unsigned int)u) << 16;
    return v.f;
}

__device__ __forceinline__ float gelu_new_f(float x) {
    float t = 0.7978845608028654f * x * (1.0f + 0.044715f * x * x);
    t = fminf(fmaxf(t, -15.f), 15.f);
    float e = __expf(-2.0f * t);
    float th = (1.0f - e) / (1.0f + e);
    return 0.5f * x * (1.0f + th);
}

// fp32 [R][C] -> bf16 [C][R], optional per-input-row scale (folds ln_weight into Wd)
__global__ void transpose_cvt(const float* __restrict__ in, unsigned short* __restrict__ out,
                              const float* __restrict__ rowscale, int R, int C) {
    __shared__ float t[32][33];
    int r0 = blockIdx.y * 32, c0 = blockIdx.x * 32;
    int tx = threadIdx.x, ty = threadIdx.y;
    #pragma unroll
    for (int j = 0; j < 32; j += 8) {
        float sc = rowscale ? rowscale[r0 + ty + j] : 1.0f;
        t[ty + j][tx] = sc * in[(size_t)(r0 + ty + j) * C + c0 + tx];
    }
    __syncthreads();
    #pragma unroll
    for (int j = 0; j < 32; j += 8)
        out[(size_t)(c0 + ty + j) * R + r0 + tx] = f2bf(t[tx][ty + j]);
}

// svec[a] = sum_h bf16(lnw[h]*wd[h][a])  (same rounded weights the MFMA sees)
// tvec[a] = b_down[a] + sum_h lnb[h]*wd[h][a]
__global__ void make_corr(const unsigned short* __restrict__ WdT, const float* __restrict__ wd,
                          const float* __restrict__ lnb, const float* __restrict__ bdn,
                          float* __restrict__ svec, float* __restrict__ tvec) {
    int a = threadIdx.x;                       // 256 threads, 1 block
    float s = 0.f;
    const s16x8* row = (const s16x8*)(WdT + (size_t)a * HID);
    #pragma unroll 4
    for (int i = 0; i < HID / 8; ++i) {
        s16x8 v = row[i];
        #pragma unroll
        for (int j = 0; j < 8; ++j) s += bf2f((unsigned short)v[j]);
    }
    svec[a] = s;
    float t = bdn[a];
    for (int h = 0; h < HID; ++h) t += lnb[h] * wd[(size_t)h * ADP + a];
    tvec[a] = t;
}

__global__ __launch_bounds__(256, 4)
void adapter_fused(const float* __restrict__ x,
                   const float* __restrict__ bup,
                   const float* __restrict__ svec, const float* __restrict__ tvec,
                   const unsigned short* __restrict__ WdT,   // [ADP][HID] bf16, lnw folded
                   const unsigned short* __restrict__ WuT,   // [HID][ADP] bf16
                   float* __restrict__ out)
{
    __shared__ unsigned short a_h[MB][264];   // raw-x chunk (GEMM1), then h (GEMM2)
    __shared__ float ep[4][16][68];           // per-wave epilogue staging
    __shared__ float stats[MB][2];            // mean, rstd
    __shared__ float sv_s[ADP], tv_s[ADP];

    const int tid  = threadIdx.x;
    const int wv   = tid >> 6;
    const int lane = tid & 63;
    const int q    = lane >> 4;
    const int l15  = lane & 15;
    const long row0 = (long)blockIdx.x * MB;

    sv_s[tid] = svec[tid];
    tv_s[tid] = tvec[tid];

    const int r   = tid >> 3;      // 32 rows, 8 threads per row
    const int sub = tid & 7;

    f32x4 c1[2][4];
    #pragma unroll
    for (int a = 0; a < 2; ++a)
        #pragma unroll
        for (int b = 0; b < 4; ++b)
            c1[a][b] = (f32x4){0.f, 0.f, 0.f, 0.f};

    float sum1 = 0.f, sum2 = 0.f;

    // ---- GEMM1 on RAW x (single pass: stage bf16 + accumulate LN moments) ----
    for (int kc = 0; kc < 4; ++kc) {
        const f32x4* xr = (const f32x4*)(x + (row0 + r) * HID + kc * 256);
        #pragma unroll
        for (int i = 0; i < 8; ++i) {
            int f4 = sub + 8 * i;
            f32x4 v = __builtin_nontemporal_load(&xr[f4]);
            sum1 += v[0] + v[1] + v[2] + v[3];
            sum2 += v[0] * v[0] + v[1] * v[1] + v[2] * v[2] + v[3] * v[3];
            ushort4 o;
            o.x = f2bf(v[0]); o.y = f2bf(v[1]); o.z = f2bf(v[2]); o.w = f2bf(v[3]);
            *(ushort4*)&a_h[r][f4 * 4] = o;
        }
        __syncthreads();
        const int nb = wv * 64;
        #pragma unroll
        for (int ks = 0; ks < 8; ++ks) {
            int kof = ks * 32 + q * 8;
            s16x8 af[2], bfr[4];
            af[0] = *(const s16x8*)&a_h[l15][kof];
            af[1] = *(const s16x8*)&a_h[16 + l15][kof];
            #pragma unroll
            for (int nt = 0; nt < 4; ++nt)
                bfr[nt] = *(const s16x8*)&WdT[(size_t)(nb + nt * 16 + l15) * HID + kc * 256 + kof];
            #pragma unroll
            for (int mt = 0; mt < 2; ++mt)
                #pragma unroll
                for (int nt = 0; nt < 4; ++nt)
                    c1[mt][nt] = __builtin_amdgcn_mfma_f32_16x16x32_bf16(af[mt], bfr[nt], c1[mt][nt], 0, 0, 0);
        }
        __syncthreads();
    }

    // ---- finalize LN statistics (8 threads per row -> shuffle reduce) ----
    sum1 += __shfl_xor(sum1, 1); sum2 += __shfl_xor(sum2, 1);
    sum1 += __shfl_xor(sum1, 2); sum2 += __shfl_xor(sum2, 2);
    sum1 += __shfl_xor(sum1, 4); sum2 += __shfl_xor(sum2, 4);
    if (sub == 0) {
        float mean = sum1 * (1.f / HID);
        float var  = sum2 * (1.f / HID) - mean * mean;
        stats[r][0] = mean;
        stats[r][1] = rsqrtf(var + 1e-5f);
    }
    __syncthreads();

    // ---- LN correction + gelu -> bf16 h, reuse a_h as [32][256] ----
    #pragma unroll
    for (int mt = 0; mt < 2; ++mt)
        #pragma unroll
        for (int nt = 0; nt < 4; ++nt) {
            int a = wv * 64 + nt * 16 + l15;
            float sv = sv_s[a], tv = tv_s[a];
            #pragma unroll
            for (int rr = 0; rr < 4; ++rr) {
                int m = mt * 16 + q * 4 + rr;
                float mean = stats[m][0], rstd = stats[m][1];
                float c = rstd * (c1[mt][nt][rr] - mean * sv) + tv;
                a_h[m][a] = f2bf(gelu_new_f(c));
            }
        }
    __syncthreads();

    // ---- GEMM2: C2[32x1024] = h[32x256] * Wu[256x1024], fused epilogue ----
    for (int ncc = 0; ncc < 4; ++ncc) {
        const int cb = wv * 256 + ncc * 64;
        f32x4 c2[2][4];
        #pragma unroll
        for (int a = 0; a < 2; ++a)
            #pragma unroll
            for (int b = 0; b < 4; ++b)
                c2[a][b] = (f32x4){0.f, 0.f, 0.f, 0.f};
        #pragma unroll
        for (int ks = 0; ks < 8; ++ks) {
            int kof = ks * 32 + q * 8;
            s16x8 af[2], bfr[4];
            af[0] = *(const s16x8*)&a_h[l15][kof];
            af[1] = *(const s16x8*)&a_h[16 + l15][kof];
            #pragma unroll
            for (int nt = 0; nt < 4; ++nt)
                bfr[nt] = *(const s16x8*)&WuT[(size_t)(cb + nt * 16 + l15) * ADP + kof];
            #pragma unroll
            for (int mt = 0; mt < 2; ++mt)
                #pragma unroll
                for (int nt = 0; nt < 4; ++nt)
                    c2[mt][nt] = __builtin_amdgcn_mfma_f32_16x16x32_bf16(af[mt], bfr[nt], c2[mt][nt], 0, 0, 0);
        }
        // epilogue: stage 16x64 tile in LDS -> coalesced float4 out with residual + b_up
        #pragma unroll
        for (int mt = 0; mt < 2; ++mt) {
            #pragma unroll
            for (int nt = 0; nt < 4; ++nt)
                #pragma unroll
                for (int rr = 0; rr < 4; ++rr)
                    ep[wv][q * 4 + rr][nt * 16 + l15] = c2[mt][nt][rr];
            __builtin_amdgcn_s_waitcnt(0xc07f);   // lgkmcnt(0): wave-local LDS drain
            int rr2 = lane >> 2, c4 = lane & 3;
            long gm = row0 + mt * 16 + rr2;
            const f32x4* xr = (const f32x4*)(x + gm * HID + cb);
            const f32x4* bu = (const f32x4*)(bup + cb);
            f32x4* orow     = (f32x4*)(out + gm * HID + cb);
            #pragma unroll
            for (int i = 0; i < 4; ++i) {
                int f4 = i * 4 + c4;
                f32x4 v  = *(const f32x4*)&ep[wv][rr2][f4 * 4];
                f32x4 rs = __builtin_nontemporal_load(&xr[f4]);
                f32x4 b4 = bu[f4];
                v += rs + b4;
                __builtin_nontemporal_store(v, &orow[f4]);
            }
            __builtin_amdgcn_s_waitcnt(0xc07f);   // drain reads before next tile overwrites
        }
    }
}

extern "C" void kernel_launch(void* const* d_in, const int* in_sizes, int n_in,
                              void* d_out, int out_size, void* d_ws, size_t ws_size,
                              hipStream_t stream) {
    const float* x   = (const float*)d_in[0];
    const float* lnw = (const float*)d_in[1];
    const float* lnb = (const float*)d_in[2];
    const float* wd  = (const float*)d_in[3];
    const float* bd  = (const float*)d_in[4];
    const float* wu  = (const float*)d_in[5];
    const float* bu  = (const float*)d_in[6];
    float* out = (float*)d_out;

    unsigned short* WdT = (unsigned short*)d_ws;        // [256][1024] bf16 (lnw folded)
    unsigned short* WuT = WdT + (size_t)HID * ADP;      // [1024][256] bf16
    float* svec = (float*)(WuT + (size_t)HID * ADP);    // [256]
    float* tvec = svec + ADP;                           // [256]

    // w_down: [1024][256] -> WdT [256][1024], scaled by ln_weight[h]
    transpose_cvt<<<dim3(ADP / 32, HID / 32), dim3(32, 8), 0, stream>>>(wd, WdT, lnw, HID, ADP);
    // w_up:   [256][1024] -> WuT [1024][256]
    transpose_cvt<<<dim3(HID / 32, ADP / 32), dim3(32, 8), 0, stream>>>(wu, WuT, nullptr, ADP, HID);
    // LN-linearity correction vectors
    make_corr<<<1, 256, 0, stream>>>(WdT, wd, lnb, bd, svec, tvec);

    const int rows = in_sizes[0] / HID;                 // 32768
    adapter_fused<<<rows / MB, 256, 0, stream>>>(x, bu, svec, tvec, WdT, WuT, out);
}

// Round 3
// 338.944 us; speedup vs baseline: 1.3450x; 1.3450x over previous
//
#include <hip/hip_runtime.h>

#define HID 1024
#define ADP 256
#define MB  32

typedef short s16x8 __attribute__((ext_vector_type(8)));
typedef unsigned short u16x8 __attribute__((ext_vector_type(8)));
typedef float f32x4 __attribute__((ext_vector_type(4)));

__device__ __forceinline__ unsigned short f2bf(float f) {
    union { float f; unsigned int u; } v; v.f = f;
    unsigned int r = v.u + 0x7fffu + ((v.u >> 16) & 1u);   // round-to-nearest-even
    return (unsigned short)(r >> 16);
}

__device__ __forceinline__ float bf2f(unsigned short u) {
    union { unsigned int u; float f; } v; v.u = ((unsigned int)u) << 16;
    return v.f;
}

__device__ __forceinline__ float gelu_new_f(float x) {
    float t = 0.7978845608028654f * x * (1.0f + 0.044715f * x * x);
    t = fminf(fmaxf(t, -15.f), 15.f);
    float e = __expf(-2.0f * t);
    float th = (1.0f - e) / (1.0f + e);
    return 0.5f * x * (1.0f + th);
}

// Pack W [K][N] fp32 -> bf16 MFMA-fragment tiles.
// Tile (nti, kti) covers rows n = nti*16.., cols k = kti*32..; tile id = nti*(K/32)+kti.
// Within tile, offset (q*16+l15)*8+e holds W[kti*32+q*8+e][nti*16+l15] * scale[k].
// A wave then loads its fragment as 64 lanes x 16B contiguous (1KB per tile).
__global__ void pack_b(const float* __restrict__ in, unsigned short* __restrict__ out,
                       const float* __restrict__ scale, int K, int N) {
    __shared__ unsigned short sh[32][72];
    int k0 = blockIdx.x * 32, n0 = blockIdx.y * 64;
    int t = threadIdx.x;
    int r = t >> 3, cg = t & 7;                 // 32 rows x 8 col-groups
    const float* src = in + (size_t)(k0 + r) * N + n0 + cg * 8;
    float sc = scale ? scale[k0 + r] : 1.0f;
    f32x4 v0 = *(const f32x4*)(src);
    f32x4 v1 = *(const f32x4*)(src + 4);
    #pragma unroll
    for (int e = 0; e < 4; ++e) {
        sh[r][cg * 8 + e]     = f2bf(sc * v0[e]);
        sh[r][cg * 8 + 4 + e] = f2bf(sc * v1[e]);
    }
    __syncthreads();
    int tile = t >> 6, l = t & 63, q = l >> 4, l15 = l & 15;
    u16x8 o;
    #pragma unroll
    for (int e = 0; e < 8; ++e)
        o[e] = sh[q * 8 + e][tile * 16 + l15];
    size_t tid_g = (size_t)(blockIdx.y * 4 + tile) * (K / 32) + blockIdx.x;
    *(u16x8*)(out + tid_g * 512 + (size_t)l * 8) = o;
}

// svec[a] = sum_h bf16(lnw[h]*wd[h][a])  (matches pack_b rounding)
// tvec[a] = b_down[a] + sum_h lnb[h]*wd[h][a]
// One wave per 'a'; lanes parallel over h.
__global__ void make_corr(const float* __restrict__ wd, const float* __restrict__ lnw,
                          const float* __restrict__ lnb, const float* __restrict__ bdn,
                          float* __restrict__ svec, float* __restrict__ tvec) {
    int w = threadIdx.x >> 6, lane = threadIdx.x & 63;
    int a = blockIdx.x * 4 + w;
    float sv = 0.f, tv = 0.f;
    #pragma unroll 4
    for (int i = 0; i < 16; ++i) {
        int h = lane + 64 * i;
        float wv_ = wd[(size_t)h * ADP + a];
        sv += bf2f(f2bf(lnw[h] * wv_));
        tv += lnb[h] * wv_;
    }
    #pragma unroll
    for (int s = 1; s < 64; s <<= 1) { sv += __shfl_xor(sv, s); tv += __shfl_xor(tv, s); }
    if (lane == 0) { svec[a] = sv; tvec[a] = bdn[a] + tv; }
}

__global__ __launch_bounds__(256, 4)
void adapter_fused(const float* __restrict__ x,
                   const float* __restrict__ bup,
                   const float* __restrict__ svec, const float* __restrict__ tvec,
                   const unsigned short* __restrict__ WdP,   // packed [16 nti][32 kti] tiles
                   const unsigned short* __restrict__ WuP,   // packed [64 nti][8 kti] tiles
                   float* __restrict__ out)
{
    __shared__ unsigned short a_h[MB][264];   // raw-x chunk (GEMM1), then h (GEMM2)
    __shared__ float ep[4][16][68];           // per-wave epilogue staging
    __shared__ float stats[MB][2];            // mean, rstd
    __shared__ float sv_s[ADP], tv_s[ADP];

    const int tid  = threadIdx.x;
    const int wv   = tid >> 6;
    const int lane = tid & 63;
    const int q    = lane >> 4;
    const int l15  = lane & 15;
    const long row0 = (long)blockIdx.x * MB;

    sv_s[tid] = svec[tid];
    tv_s[tid] = tvec[tid];

    const int r   = tid >> 3;      // 32 rows, 8 threads per row
    const int sub = tid & 7;

    f32x4 c1[2][4];
    #pragma unroll
    for (int a = 0; a < 2; ++a)
        #pragma unroll
        for (int b = 0; b < 4; ++b)
            c1[a][b] = (f32x4){0.f, 0.f, 0.f, 0.f};

    float sum1 = 0.f, sum2 = 0.f;

    // prefetch chunk 0 into registers
    f32x4 xv[8];
    {
        const f32x4* xr = (const f32x4*)(x + (row0 + r) * HID);
        #pragma unroll
        for (int i = 0; i < 8; ++i)
            xv[i] = __builtin_nontemporal_load(&xr[sub + 8 * i]);
    }

    // ---- GEMM1 on RAW x (stage bf16 + LN moments; next chunk prefetched under MFMA) ----
    for (int kc = 0; kc < 4; ++kc) {
        #pragma unroll
        for (int i = 0; i < 8; ++i) {
            int f4 = sub + 8 * i;
            f32x4 v = xv[i];
            sum1 += v[0] + v[1] + v[2] + v[3];
            sum2 += v[0] * v[0] + v[1] * v[1] + v[2] * v[2] + v[3] * v[3];
            ushort4 o;
            o.x = f2bf(v[0]); o.y = f2bf(v[1]); o.z = f2bf(v[2]); o.w = f2bf(v[3]);
            *(ushort4*)&a_h[r][f4 * 4] = o;
        }
        __syncthreads();
        if (kc < 3) {   // issue next chunk's loads; they fly under the MFMA phase
            const f32x4* xr = (const f32x4*)(x + (row0 + r) * HID + (kc + 1) * 256);
            #pragma unroll
            for (int i = 0; i < 8; ++i)
                xv[i] = __builtin_nontemporal_load(&xr[sub + 8 * i]);
        }
        #pragma unroll
        for (int ks = 0; ks < 8; ++ks) {
            int kof = ks * 32 + q * 8;
            s16x8 af[2], bfr[4];
            af[0] = *(const s16x8*)&a_h[l15][kof];
            af[1] = *(const s16x8*)&a_h[16 + l15][kof];
            #pragma unroll
            for (int nt = 0; nt < 4; ++nt)
                bfr[nt] = *(const s16x8*)&WdP[(((size_t)(wv * 4 + nt) * 32) + kc * 8 + ks) * 512 + lane * 8];
            #pragma unroll
            for (int mt = 0; mt < 2; ++mt)
                #pragma unroll
                for (int nt = 0; nt < 4; ++nt)
                    c1[mt][nt] = __builtin_amdgcn_mfma_f32_16x16x32_bf16(af[mt], bfr[nt], c1[mt][nt], 0, 0, 0);
        }
        __syncthreads();
    }

    // ---- finalize LN statistics (8 threads per row -> shuffle reduce) ----
    sum1 += __shfl_xor(sum1, 1); sum2 += __shfl_xor(sum2, 1);
    sum1 += __shfl_xor(sum1, 2); sum2 += __shfl_xor(sum2, 2);
    sum1 += __shfl_xor(sum1, 4); sum2 += __shfl_xor(sum2, 4);
    if (sub == 0) {
        float mean = sum1 * (1.f / HID);
        float var  = sum2 * (1.f / HID) - mean * mean;
        stats[r][0] = mean;
        stats[r][1] = rsqrtf(var + 1e-5f);
    }
    __syncthreads();

    // ---- LN correction + gelu -> bf16 h, reuse a_h as [32][256] ----
    #pragma unroll
    for (int mt = 0; mt < 2; ++mt)
        #pragma unroll
        for (int nt = 0; nt < 4; ++nt) {
            int a = wv * 64 + nt * 16 + l15;
            float sv = sv_s[a], tv = tv_s[a];
            #pragma unroll
            for (int rr = 0; rr < 4; ++rr) {
                int m = mt * 16 + q * 4 + rr;
                float mean = stats[m][0], rstd = stats[m][1];
                float c = rstd * (c1[mt][nt][rr] - mean * sv) + tv;
                a_h[m][a] = f2bf(gelu_new_f(c));
            }
        }
    __syncthreads();

    // ---- GEMM2: C2[32x1024] = h[32x256] * Wu[256x1024], fused epilogue ----
    for (int ncc = 0; ncc < 4; ++ncc) {
        const int cb = wv * 256 + ncc * 64;
        f32x4 c2[2][4];
        #pragma unroll
        for (int a = 0; a < 2; ++a)
            #pragma unroll
            for (int b = 0; b < 4; ++b)
                c2[a][b] = (f32x4){0.f, 0.f, 0.f, 0.f};
        #pragma unroll
        for (int ks = 0; ks < 8; ++ks) {
            int kof = ks * 32 + q * 8;
            s16x8 af[2], bfr[4];
            af[0] = *(const s16x8*)&a_h[l15][kof];
            af[1] = *(const s16x8*)&a_h[16 + l15][kof];
            #pragma unroll
            for (int nt = 0; nt < 4; ++nt)
                bfr[nt] = *(const s16x8*)&WuP[(((size_t)(wv * 16 + ncc * 4 + nt) * 8) + ks) * 512 + lane * 8];
            #pragma unroll
            for (int mt = 0; mt < 2; ++mt)
                #pragma unroll
                for (int nt = 0; nt < 4; ++nt)
                    c2[mt][nt] = __builtin_amdgcn_mfma_f32_16x16x32_bf16(af[mt], bfr[nt], c2[mt][nt], 0, 0, 0);
        }
        // epilogue: stage 16x64 tile in LDS -> coalesced float4 out with residual + b_up
        #pragma unroll
        for (int mt = 0; mt < 2; ++mt) {
            #pragma unroll
            for (int nt = 0; nt < 4; ++nt)
                #pragma unroll
                for (int rr = 0; rr < 4; ++rr)
                    ep[wv][q * 4 + rr][nt * 16 + l15] = c2[mt][nt][rr];
            __builtin_amdgcn_s_waitcnt(0xc07f);   // lgkmcnt(0): wave-local LDS drain
            int rr2 = lane >> 2, c4 = lane & 3;
            long gm = row0 + mt * 16 + rr2;
            const f32x4* xr = (const f32x4*)(x + gm * HID + cb);
            const f32x4* bu = (const f32x4*)(bup + cb);
            f32x4* orow     = (f32x4*)(out + gm * HID + cb);
            #pragma unroll
            for (int i = 0; i < 4; ++i) {
                int f4 = i * 4 + c4;
                f32x4 v  = *(const f32x4*)&ep[wv][rr2][f4 * 4];
                f32x4 rs = __builtin_nontemporal_load(&xr[f4]);
                f32x4 b4 = bu[f4];
                v += rs + b4;
                __builtin_nontemporal_store(v, &orow[f4]);
            }
            __builtin_amdgcn_s_waitcnt(0xc07f);   // drain reads before next tile overwrites
        }
    }
}

extern "C" void kernel_launch(void* const* d_in, const int* in_sizes, int n_in,
                              void* d_out, int out_size, void* d_ws, size_t ws_size,
                              hipStream_t stream) {
    const float* x   = (const float*)d_in[0];
    const float* lnw = (const float*)d_in[1];
    const float* lnb = (const float*)d_in[2];
    const float* wd  = (const float*)d_in[3];
    const float* bd  = (const float*)d_in[4];
    const float* wu  = (const float*)d_in[5];
    const float* bu  = (const float*)d_in[6];
    float* out = (float*)d_out;

    unsigned short* WdP = (unsigned short*)d_ws;        // packed wd (lnw folded), 512KB
    unsigned short* WuP = WdP + (size_t)HID * ADP;      // packed wu, 512KB
    float* svec = (float*)(WuP + (size_t)HID * ADP);    // [256]
    float* tvec = svec + ADP;                           // [256]

    // wd [K=1024][N=256], lnw folded along K
    pack_b<<<dim3(HID / 32, ADP / 64), 256, 0, stream>>>(wd, WdP, lnw, HID, ADP);
    // wu [K=256][N=1024]
    pack_b<<<dim3(ADP / 32, HID / 64), 256, 0, stream>>>(wu, WuP, nullptr, ADP, HID);
    // LN-linearity correction vectors (parallel: one wave per column)
    make_corr<<<ADP / 4, 256, 0, stream>>>(wd, lnw, lnb, bd, svec, tvec);

    const int rows = in_sizes[0] / HID;                 // 32768
    adapter_fused<<<rows / MB, 256, 0, stream>>>(x, bu, svec, tvec, WdP, WuP, out);
}